// Round 11
// baseline (155.766 us; speedup 1.0000x reference)
//
#include <hip/hip_runtime.h>
#include <hip/hip_bf16.h>

typedef __bf16 bf16x8 __attribute__((ext_vector_type(8)));
typedef float f32x4 __attribute__((ext_vector_type(4)));
typedef _Float16 f16x2 __attribute__((ext_vector_type(2)));

#define GLOBAL_AS(p) ((const __attribute__((address_space(1))) void*)(p))
#define LDS_AS(p)    ((__attribute__((address_space(3))) void*)(p))

static __device__ __forceinline__ unsigned short f2bf(float f) {
    union { float f; unsigned u; } v; v.f = f;
    unsigned r = v.u + 0x7FFFu + ((v.u >> 16) & 1u);
    return (unsigned short)(r >> 16);
}

// ---------------------------------------------------------------------------
// xb2 layout: 8200 rows of 1024 bf16. Batch b: zero row at b*1025, then
// x[b,0..1023] at rows b*1025+1 .. b*1025+1024. So [x[m-1], x[m]] is 2048
// CONTIGUOUS elements starting at row (m + (m>>10)).
// ---------------------------------------------------------------------------
__global__ void prep_xb(const float* __restrict__ x, unsigned short* __restrict__ xb2) {
    const int bid = blockIdx.x;
    const int c = threadIdx.x * 4;
    if (bid < 8192) {
        const int dst = bid + (bid >> 10) + 1;
        float4 v = *reinterpret_cast<const float4*>(x + (size_t)bid * 1024 + c);
        ushort4 b = make_ushort4(f2bf(v.x), f2bf(v.y), f2bf(v.z), f2bf(v.w));
        *reinterpret_cast<ushort4*>(xb2 + (size_t)dst * 1024 + c) = b;
    } else {
        const int zr = (bid - 8192) * 1025;
        *reinterpret_cast<ushort4*>(xb2 + (size_t)zr * 1024 + c) = make_ushort4(0, 0, 0, 0);
    }
}

// ---------------------------------------------------------------------------
// Transpose kernel f32 [2048][3072] (W,D flattened) -> KT bf16 [3072][2048]
// ---------------------------------------------------------------------------
__global__ void prep_kt(const float* __restrict__ K, unsigned short* __restrict__ KT) {
    __shared__ float tile[64][65];
    const int bi = blockIdx.x;   // kd tile: 32
    const int bj = blockIdx.y;   // u  tile: 48
    const int tx = threadIdx.x & 63;
    const int ty = threadIdx.x >> 6;   // 0..3

#pragma unroll
    for (int i = 0; i < 16; ++i) {
        int r = ty * 16 + i;
        tile[r][tx] = K[(size_t)(bi * 64 + r) * 3072 + bj * 64 + tx];
    }
    __syncthreads();
#pragma unroll
    for (int i = 0; i < 16; ++i) {
        int r = ty * 16 + i;
        KT[(size_t)(bj * 64 + r) * 2048 + bi * 64 + tx] = f2bf(tile[tx][r]);
    }
}

// ---------------------------------------------------------------------------
// GEMM (round-7 measured optimum, 966 TF / 106.5 us — kept verbatim):
// gates[8192][3072] = Acat(xb2)[8192][2048] * KT[3072][2048]^T + bias,
// fused activation, f16 out. 128x128 tile, BK=64, 4 waves, global_load_lds
// w=16, pre-swizzled source + XOR-swizzled ds_read (0 bank conflicts).
// Explicit dbuf/counted-vmcnt/asm-ds_read variants all measured neutral or
// worse (rounds 3,4,8,9,10): implicit 2-blocks/CU overlap saturates this.
// ---------------------------------------------------------------------------
__global__ __launch_bounds__(256, 2)
void gemm_gates(const unsigned short* __restrict__ xb2,
                const unsigned short* __restrict__ BT,
                const float* __restrict__ bias,
                _Float16* __restrict__ G) {
    __shared__ __align__(16) unsigned short As[128 * 64];
    __shared__ __align__(16) unsigned short Bs[128 * 64];

    const int tid  = threadIdx.x;
    const int lane = tid & 63;
    const int wid  = tid >> 6;
    const int wr   = wid >> 1, wc = wid & 1;
    const int m0   = blockIdx.y * 128;
    const int n0   = blockIdx.x * 128;

    f32x4 acc[4][4] = {};

    const int sr = lane >> 3;   // row within 8-row group
    const int sc = lane & 7;    // 16B chunk slot this lane writes

    const unsigned short* srcA[4];
    const unsigned short* srcB[4];
#pragma unroll
    for (int i = 0; i < 4; ++i) {
        const int r  = wid * 32 + i * 8 + sr;
        const int cc = sc ^ (r & 7);
        const int m  = m0 + r;
        srcA[i] = xb2 + (size_t)(m + (m >> 10)) * 1024 + cc * 8;  // 2048 contiguous K
        srcB[i] = BT  + (size_t)(n0 + r) * 2048 + cc * 8;
    }

    for (int kt = 0; kt < 32; ++kt) {
        const int kb = kt * 64;
#pragma unroll
        for (int i = 0; i < 4; ++i) {
            const int r0 = wid * 32 + i * 8;
            __builtin_amdgcn_global_load_lds(GLOBAL_AS(srcA[i] + kb), LDS_AS(As + r0 * 64), 16, 0, 0);
            __builtin_amdgcn_global_load_lds(GLOBAL_AS(srcB[i] + kb), LDS_AS(Bs + r0 * 64), 16, 0, 0);
        }
        __syncthreads();

#pragma unroll
        for (int ks = 0; ks < 2; ++ks) {
            bf16x8 af[4], bg[4];
#pragma unroll
            for (int m = 0; m < 4; ++m) {
                const int row = wr * 64 + m * 16 + (lane & 15);
                const int c   = ks * 4 + (lane >> 4);
                const int p   = c ^ (row & 7);
                af[m] = *reinterpret_cast<const bf16x8*>(As + row * 64 + p * 8);
            }
#pragma unroll
            for (int n = 0; n < 4; ++n) {
                const int row = wc * 64 + n * 16 + (lane & 15);
                const int c   = ks * 4 + (lane >> 4);
                const int p   = c ^ (row & 7);
                bg[n] = *reinterpret_cast<const bf16x8*>(Bs + row * 64 + p * 8);
            }
#pragma unroll
            for (int m = 0; m < 4; ++m)
#pragma unroll
                for (int n = 0; n < 4; ++n)
                    acc[m][n] = __builtin_amdgcn_mfma_f32_16x16x32_bf16(af[m], bg[n], acc[m][n], 0, 0, 0);
        }
        __syncthreads();
    }

    // Epilogue: bias + activation, store f16. Gate region uniform per block.
    const int rgn = n0 >> 10;   // 0=z(tanh), 1=f, 2=o
#pragma unroll
    for (int m = 0; m < 4; ++m) {
#pragma unroll
        for (int n = 0; n < 4; ++n) {
            const int col = n0 + wc * 64 + n * 16 + (lane & 15);
            const float bv = bias[col];
#pragma unroll
            for (int v = 0; v < 4; ++v) {
                const int row = m0 + wr * 64 + m * 16 + ((lane >> 4) * 4) + v;
                const float g = acc[m][n][v] + bv;
                float val;
                if (rgn == 0) {
                    float s = 1.0f / (1.0f + __expf(-2.0f * g));
                    val = 2.0f * s - 1.0f;                       // tanh
                } else {
                    val = 1.0f / (1.0f + __expf(-g));            // sigmoid
                }
                G[(size_t)row * 3072 + col] = (_Float16)val;
            }
        }
    }
}

// ---------------------------------------------------------------------------
// Chunked parallel scan, 2 u-chains per thread (f16x2 loads = 256B/wave-instr
// vs scalar 128B; G is L3-resident). Pass 1: per-(chain,chunk) compose (A,B)
// for chunks 0..6; stored as float4 pairs {A0,B0,A1,B1}.
// ---------------------------------------------------------------------------
__global__ void scan_pass1(const _Float16* __restrict__ G, float4* __restrict__ AB4) {
    const int bid = blockIdx.x;        // 224 blocks = 8 b x 7 c x 4 ug, 128 thr
    const int b   = bid / 28;
    const int r   = bid % 28;
    const int c   = r >> 2;            // chunk 0..6
    const int ug  = r & 3;
    const int u0  = ug * 256 + threadIdx.x * 2;
    const _Float16* g = G + (size_t)(b * 1024 + c * 128) * 3072 + u0;
    float A0 = 1.f, B0 = 0.f, A1 = 1.f, B1 = 0.f;
#pragma unroll 16
    for (int i = 0; i < 128; ++i) {
        const f16x2 zv = *reinterpret_cast<const f16x2*>(g + (size_t)i * 3072);
        const f16x2 fv = *reinterpret_cast<const f16x2*>(g + (size_t)i * 3072 + 1024);
        const f16x2 ov = *reinterpret_cast<const f16x2*>(g + (size_t)i * 3072 + 2048);
        const float z0 = (float)zv[0], f0 = (float)fv[0], o0 = (float)ov[0];
        const float z1 = (float)zv[1], f1 = (float)fv[1], o1 = (float)ov[1];
        const float a0 = o0 * f0, bb0 = o0 * (1.f - f0) * z0;
        const float a1 = o1 * f1, bb1 = o1 * (1.f - f1) * z1;
        A0 = a0 * A0; B0 = a0 * B0 + bb0;
        A1 = a1 * A1; B1 = a1 * B1 + bb1;
    }
    AB4[((size_t)(b * 8 + c) * 1024 + u0) >> 1] = make_float4(A0, B0, A1, B1);
}

// 256 blocks x 128 thr (b x 8, c x 8, ug x 4), 2 u per thread; prefix from
// AB4 (one float4 per chunk), rescan with float2 stores.
__global__ void scan_pass23(const _Float16* __restrict__ G, const float4* __restrict__ AB4,
                            float* __restrict__ out) {
    const int bid = blockIdx.x;
    const int b   = bid >> 5;
    const int r   = bid & 31;
    const int c   = r >> 2;            // chunk 0..7 (block-uniform)
    const int ug  = r & 3;
    const int u0  = ug * 256 + threadIdx.x * 2;

    float h0 = 0.f, h1 = 0.f;
    for (int j = 0; j < c; ++j) {      // block-uniform trip count
        const float4 p = AB4[((size_t)(b * 8 + j) * 1024 + u0) >> 1];
        h0 = p.x * h0 + p.y;
        h1 = p.z * h1 + p.w;
    }
    const _Float16* g = G + (size_t)(b * 1024 + c * 128) * 3072 + u0;
    float* o = out + (size_t)(b * 1024 + c * 128) * 1024 + u0;
#pragma unroll 16
    for (int i = 0; i < 128; ++i) {
        const f16x2 zv = *reinterpret_cast<const f16x2*>(g + (size_t)i * 3072);
        const f16x2 fv = *reinterpret_cast<const f16x2*>(g + (size_t)i * 3072 + 1024);
        const f16x2 ov = *reinterpret_cast<const f16x2*>(g + (size_t)i * 3072 + 2048);
        const float z0 = (float)zv[0], f0 = (float)fv[0], o0 = (float)ov[0];
        const float z1 = (float)zv[1], f1 = (float)fv[1], o1 = (float)ov[1];
        h0 = o0 * (f0 * h0 + (1.f - f0) * z0);
        h1 = o1 * (f1 * h1 + (1.f - f1) * z1);
        *reinterpret_cast<float2*>(o + (size_t)i * 1024) = make_float2(h0, h1);
    }
}

// ---------------------------------------------------------------------------
extern "C" void kernel_launch(void* const* d_in, const int* in_sizes, int n_in,
                              void* d_out, int out_size, void* d_ws, size_t ws_size,
                              hipStream_t stream) {
    const float* x    = (const float*)d_in[0];   // [8,1024,1024]
    const float* kern = (const float*)d_in[1];   // [2,1024,3072]
    const float* bias = (const float*)d_in[2];   // [3072]
    float* out = (float*)d_out;                  // [8,1024,1024]

    char* ws = (char*)d_ws;
    unsigned short* xb2 = (unsigned short*)ws;                  // 8200*1024*2 = 16,793,600 B
    unsigned short* KT  = (unsigned short*)(ws + 16793600);     // 12,582,912 B
    _Float16* G         = (_Float16*)(ws + 29376512);           // 50,331,648 B
    float4* AB4         = (float4*)(ws + 79708160);             //    524,288 B

    prep_xb<<<dim3(8200), dim3(256), 0, stream>>>(x, xb2);
    prep_kt<<<dim3(32, 48), dim3(256), 0, stream>>>(kern, KT);
    gemm_gates<<<dim3(24, 64), dim3(256), 0, stream>>>(xb2, KT, bias, G);
    scan_pass1<<<dim3(224), dim3(128), 0, stream>>>(G, AB4);
    scan_pass23<<<dim3(256), dim3(128), 0, stream>>>(G, AB4, out);
}

// Round 12
// 152.063 us; speedup vs baseline: 1.0243x; 1.0243x over previous
//
#include <hip/hip_runtime.h>
#include <hip/hip_bf16.h>

typedef __bf16 bf16x8 __attribute__((ext_vector_type(8)));
typedef float f32x4 __attribute__((ext_vector_type(4)));

#define GLOBAL_AS(p) ((const __attribute__((address_space(1))) void*)(p))
#define LDS_AS(p)    ((__attribute__((address_space(3))) void*)(p))

static __device__ __forceinline__ unsigned short f2bf(float f) {
    union { float f; unsigned u; } v; v.f = f;
    unsigned r = v.u + 0x7FFFu + ((v.u >> 16) & 1u);
    return (unsigned short)(r >> 16);
}

// ---------------------------------------------------------------------------
// xb2 layout: 8200 rows of 1024 bf16. Batch b: zero row at b*1025, then
// x[b,0..1023] at rows b*1025+1 .. b*1025+1024. So [x[m-1], x[m]] is 2048
// CONTIGUOUS elements starting at row (m + (m>>10)).
// ---------------------------------------------------------------------------
__global__ void prep_xb(const float* __restrict__ x, unsigned short* __restrict__ xb2) {
    const int bid = blockIdx.x;
    const int c = threadIdx.x * 4;
    if (bid < 8192) {
        const int dst = bid + (bid >> 10) + 1;
        float4 v = *reinterpret_cast<const float4*>(x + (size_t)bid * 1024 + c);
        ushort4 b = make_ushort4(f2bf(v.x), f2bf(v.y), f2bf(v.z), f2bf(v.w));
        *reinterpret_cast<ushort4*>(xb2 + (size_t)dst * 1024 + c) = b;
    } else {
        const int zr = (bid - 8192) * 1025;
        *reinterpret_cast<ushort4*>(xb2 + (size_t)zr * 1024 + c) = make_ushort4(0, 0, 0, 0);
    }
}

// ---------------------------------------------------------------------------
// Transpose kernel f32 [2048][3072] (W,D flattened) -> KT bf16 [3072][2048]
// ---------------------------------------------------------------------------
__global__ void prep_kt(const float* __restrict__ K, unsigned short* __restrict__ KT) {
    __shared__ float tile[64][65];
    const int bi = blockIdx.x;   // kd tile: 32
    const int bj = blockIdx.y;   // u  tile: 48
    const int tx = threadIdx.x & 63;
    const int ty = threadIdx.x >> 6;   // 0..3

#pragma unroll
    for (int i = 0; i < 16; ++i) {
        int r = ty * 16 + i;
        tile[r][tx] = K[(size_t)(bi * 64 + r) * 3072 + bj * 64 + tx];
    }
    __syncthreads();
#pragma unroll
    for (int i = 0; i < 16; ++i) {
        int r = ty * 16 + i;
        KT[(size_t)(bj * 64 + r) * 2048 + bi * 64 + tx] = f2bf(tile[tx][r]);
    }
}

// ---------------------------------------------------------------------------
// GEMM (measured optimum, 966 TF / 106.5 us): gates[8192][3072] =
// Acat(xb2)[8192][2048] * KT[3072][2048]^T + bias, fused activation, f16 out.
// 128x128 tile, BK=64, 4 waves, global_load_lds w=16, pre-swizzled source +
// XOR-swizzled ds_read (0 bank conflicts). 2D grid (24,64): consecutive
// blocks share the A m-panel (FETCH 148 MB; XCD-chunk swizzle regressed).
// Explicit dbuf/counted-vmcnt/asm-ds_read/8-phase variants all measured
// neutral or worse (rounds 3,4,8,9,10): implicit 2-blocks/CU overlap
// saturates this structure.
// ---------------------------------------------------------------------------
__global__ __launch_bounds__(256, 2)
void gemm_gates(const unsigned short* __restrict__ xb2,
                const unsigned short* __restrict__ BT,
                const float* __restrict__ bias,
                _Float16* __restrict__ G) {
    __shared__ __align__(16) unsigned short As[128 * 64];
    __shared__ __align__(16) unsigned short Bs[128 * 64];

    const int tid  = threadIdx.x;
    const int lane = tid & 63;
    const int wid  = tid >> 6;
    const int wr   = wid >> 1, wc = wid & 1;
    const int m0   = blockIdx.y * 128;
    const int n0   = blockIdx.x * 128;

    f32x4 acc[4][4] = {};

    const int sr = lane >> 3;   // row within 8-row group
    const int sc = lane & 7;    // 16B chunk slot this lane writes

    const unsigned short* srcA[4];
    const unsigned short* srcB[4];
#pragma unroll
    for (int i = 0; i < 4; ++i) {
        const int r  = wid * 32 + i * 8 + sr;
        const int cc = sc ^ (r & 7);
        const int m  = m0 + r;
        srcA[i] = xb2 + (size_t)(m + (m >> 10)) * 1024 + cc * 8;  // 2048 contiguous K
        srcB[i] = BT  + (size_t)(n0 + r) * 2048 + cc * 8;
    }

    for (int kt = 0; kt < 32; ++kt) {
        const int kb = kt * 64;
#pragma unroll
        for (int i = 0; i < 4; ++i) {
            const int r0 = wid * 32 + i * 8;
            __builtin_amdgcn_global_load_lds(GLOBAL_AS(srcA[i] + kb), LDS_AS(As + r0 * 64), 16, 0, 0);
            __builtin_amdgcn_global_load_lds(GLOBAL_AS(srcB[i] + kb), LDS_AS(Bs + r0 * 64), 16, 0, 0);
        }
        __syncthreads();

#pragma unroll
        for (int ks = 0; ks < 2; ++ks) {
            bf16x8 af[4], bg[4];
#pragma unroll
            for (int m = 0; m < 4; ++m) {
                const int row = wr * 64 + m * 16 + (lane & 15);
                const int c   = ks * 4 + (lane >> 4);
                const int p   = c ^ (row & 7);
                af[m] = *reinterpret_cast<const bf16x8*>(As + row * 64 + p * 8);
            }
#pragma unroll
            for (int n = 0; n < 4; ++n) {
                const int row = wc * 64 + n * 16 + (lane & 15);
                const int c   = ks * 4 + (lane >> 4);
                const int p   = c ^ (row & 7);
                bg[n] = *reinterpret_cast<const bf16x8*>(Bs + row * 64 + p * 8);
            }
#pragma unroll
            for (int m = 0; m < 4; ++m)
#pragma unroll
                for (int n = 0; n < 4; ++n)
                    acc[m][n] = __builtin_amdgcn_mfma_f32_16x16x32_bf16(af[m], bg[n], acc[m][n], 0, 0, 0);
        }
        __syncthreads();
    }

    // Epilogue: bias + activation, store f16. Gate region uniform per block.
    const int rgn = n0 >> 10;   // 0=z(tanh), 1=f, 2=o
#pragma unroll
    for (int m = 0; m < 4; ++m) {
#pragma unroll
        for (int n = 0; n < 4; ++n) {
            const int col = n0 + wc * 64 + n * 16 + (lane & 15);
            const float bv = bias[col];
#pragma unroll
            for (int v = 0; v < 4; ++v) {
                const int row = m0 + wr * 64 + m * 16 + ((lane >> 4) * 4) + v;
                const float g = acc[m][n][v] + bv;
                float val;
                if (rgn == 0) {
                    float s = 1.0f / (1.0f + __expf(-2.0f * g));
                    val = 2.0f * s - 1.0f;                       // tanh
                } else {
                    val = 1.0f / (1.0f + __expf(-g));            // sigmoid
                }
                G[(size_t)row * 3072 + col] = (_Float16)val;
            }
        }
    }
}

// ---------------------------------------------------------------------------
// Chunked parallel scan of h_t = o_t*(f_t*h_{t-1} + (1-f_t)*z_t)  (G is f16)
// Pass 1: per-(chain,chunk) compose (A,B); chunk 7 skipped (never consumed).
// ---------------------------------------------------------------------------
__global__ void scan_pass1(const _Float16* __restrict__ G, float2* __restrict__ AB) {
    const int bid = blockIdx.x;        // 224 blocks = 8 b x 7 c x 4 ug
    const int b   = bid / 28;
    const int r   = bid % 28;
    const int c   = r >> 2;            // chunk 0..6
    const int ug  = r & 3;
    const int u   = ug * 256 + threadIdx.x;
    const _Float16* g = G + (size_t)(b * 1024 + c * 128) * 3072 + u;
    float A = 1.f, Bv = 0.f;
#pragma unroll 8
    for (int i = 0; i < 128; ++i) {
        const float zv = (float)g[(size_t)i * 3072];
        const float fv = (float)g[(size_t)i * 3072 + 1024];
        const float ov = (float)g[(size_t)i * 3072 + 2048];
        const float a  = ov * fv;
        const float bb = ov * (1.f - fv) * zv;
        A  = a * A;
        Bv = a * Bv + bb;
    }
    AB[(size_t)(b * 8 + c) * 1024 + u] = make_float2(A, Bv);
}

// 1024 blocks x 64 threads: b x 8, c x 8, ug x 16 -> all 256 CUs covered.
__global__ void scan_pass23(const _Float16* __restrict__ G, const float2* __restrict__ AB,
                            float* __restrict__ out) {
    const int bid = blockIdx.x;
    const int b   = bid >> 7;
    const int r   = bid & 127;
    const int c   = r >> 4;            // chunk 0..7 (block-uniform)
    const int ug  = r & 15;
    const int u   = ug * 64 + threadIdx.x;

    float h = 0.f;
    for (int j = 0; j < c; ++j) {      // block-uniform trip count
        float2 p = AB[(size_t)(b * 8 + j) * 1024 + u];
        h = p.x * h + p.y;
    }
    const _Float16* g = G + (size_t)(b * 1024 + c * 128) * 3072 + u;
    float* o = out + (size_t)(b * 1024 + c * 128) * 1024 + u;
#pragma unroll 8
    for (int i = 0; i < 128; ++i) {
        const float zv = (float)g[(size_t)i * 3072];
        const float fv = (float)g[(size_t)i * 3072 + 1024];
        const float ov = (float)g[(size_t)i * 3072 + 2048];
        h = ov * (fv * h + (1.f - fv) * zv);
        o[(size_t)i * 1024] = h;
    }
}

// ---------------------------------------------------------------------------
extern "C" void kernel_launch(void* const* d_in, const int* in_sizes, int n_in,
                              void* d_out, int out_size, void* d_ws, size_t ws_size,
                              hipStream_t stream) {
    const float* x    = (const float*)d_in[0];   // [8,1024,1024]
    const float* kern = (const float*)d_in[1];   // [2,1024,3072]
    const float* bias = (const float*)d_in[2];   // [3072]
    float* out = (float*)d_out;                  // [8,1024,1024]

    char* ws = (char*)d_ws;
    unsigned short* xb2 = (unsigned short*)ws;                  // 8200*1024*2 = 16,793,600 B
    unsigned short* KT  = (unsigned short*)(ws + 16793600);     // 12,582,912 B
    _Float16* G         = (_Float16*)(ws + 29376512);           // 50,331,648 B
    float2* AB          = (float2*)(ws + 79708160);             //    524,288 B

    prep_xb<<<dim3(8200), dim3(256), 0, stream>>>(x, xb2);
    prep_kt<<<dim3(32, 48), dim3(256), 0, stream>>>(kern, KT);
    gemm_gates<<<dim3(24, 64), dim3(256), 0, stream>>>(xb2, KT, bias, G);
    scan_pass1<<<dim3(224), dim3(256), 0, stream>>>(G, AB);
    scan_pass23<<<dim3(1024), dim3(64), 0, stream>>>(G, AB, out);
}

// Round 13
// 145.955 us; speedup vs baseline: 1.0672x; 1.0419x over previous
//
#include <hip/hip_runtime.h>
#include <hip/hip_bf16.h>

typedef __bf16 bf16x8 __attribute__((ext_vector_type(8)));
typedef float f32x4 __attribute__((ext_vector_type(4)));

#define GLOBAL_AS(p) ((const __attribute__((address_space(1))) void*)(p))
#define LDS_AS(p)    ((__attribute__((address_space(3))) void*)(p))

static __device__ __forceinline__ unsigned short f2bf(float f) {
    union { float f; unsigned u; } v; v.f = f;
    unsigned r = v.u + 0x7FFFu + ((v.u >> 16) & 1u);
    return (unsigned short)(r >> 16);
}

// ---------------------------------------------------------------------------
// Merged input prep (one launch instead of two serialized ones):
//  bid <  1536: kernel transpose f32 [2048][3072] -> KT bf16 [3072][2048]
//  bid >= 1536: x f32 -> xb2 bf16 padded layout (8200 rows; zero row per
//               batch so [x[m-1],x[m]] is 2048 contiguous at row m+(m>>10)).
// kt blocks first: they fill the drain tail of the 8200 xb blocks.
// ---------------------------------------------------------------------------
__global__ void prep_inputs(const float* __restrict__ x, const float* __restrict__ K,
                            unsigned short* __restrict__ xb2, unsigned short* __restrict__ KT) {
    __shared__ float tile[64][65];
    const int bid = blockIdx.x;
    if (bid < 1536) {
        const int bi = bid & 31;      // kd tile (32)
        const int bj = bid >> 5;      // u tile (48)
        const int tx = threadIdx.x & 63;
        const int ty = threadIdx.x >> 6;   // 0..3
#pragma unroll
        for (int i = 0; i < 16; ++i) {
            int r = ty * 16 + i;
            tile[r][tx] = K[(size_t)(bi * 64 + r) * 3072 + bj * 64 + tx];
        }
        __syncthreads();
#pragma unroll
        for (int i = 0; i < 16; ++i) {
            int r = ty * 16 + i;
            KT[(size_t)(bj * 64 + r) * 2048 + bi * 64 + tx] = f2bf(tile[tx][r]);
        }
    } else {
        const int mb = bid - 1536;    // 0..8199
        const int c = threadIdx.x * 4;
        if (mb < 8192) {
            const int dst = mb + (mb >> 10) + 1;
            float4 v = *reinterpret_cast<const float4*>(x + (size_t)mb * 1024 + c);
            ushort4 b = make_ushort4(f2bf(v.x), f2bf(v.y), f2bf(v.z), f2bf(v.w));
            *reinterpret_cast<ushort4*>(xb2 + (size_t)dst * 1024 + c) = b;
        } else {
            const int zr = (mb - 8192) * 1025;
            *reinterpret_cast<ushort4*>(xb2 + (size_t)zr * 1024 + c) = make_ushort4(0, 0, 0, 0);
        }
    }
}

// ---------------------------------------------------------------------------
// GEMM (measured optimum, 966 TF / 106.5 us — kept verbatim from round 12):
// gates[8192][3072] = Acat(xb2)[8192][2048] * KT[3072][2048]^T + bias,
// fused activation, f16 out. 128x128 tile, BK=64, 4 waves, global_load_lds
// w=16, pre-swizzled source + XOR-swizzled ds_read (0 bank conflicts).
// 2D grid (24,64). Explicit dbuf/counted-vmcnt/asm-ds_read/8-phase variants
// all measured neutral or worse (rounds 3,4,8,9,10).
// ---------------------------------------------------------------------------
__global__ __launch_bounds__(256, 2)
void gemm_gates(const unsigned short* __restrict__ xb2,
                const unsigned short* __restrict__ BT,
                const float* __restrict__ bias,
                _Float16* __restrict__ G) {
    __shared__ __align__(16) unsigned short As[128 * 64];
    __shared__ __align__(16) unsigned short Bs[128 * 64];

    const int tid  = threadIdx.x;
    const int lane = tid & 63;
    const int wid  = tid >> 6;
    const int wr   = wid >> 1, wc = wid & 1;
    const int m0   = blockIdx.y * 128;
    const int n0   = blockIdx.x * 128;

    f32x4 acc[4][4] = {};

    const int sr = lane >> 3;   // row within 8-row group
    const int sc = lane & 7;    // 16B chunk slot this lane writes

    const unsigned short* srcA[4];
    const unsigned short* srcB[4];
#pragma unroll
    for (int i = 0; i < 4; ++i) {
        const int r  = wid * 32 + i * 8 + sr;
        const int cc = sc ^ (r & 7);
        const int m  = m0 + r;
        srcA[i] = xb2 + (size_t)(m + (m >> 10)) * 1024 + cc * 8;  // 2048 contiguous K
        srcB[i] = BT  + (size_t)(n0 + r) * 2048 + cc * 8;
    }

    for (int kt = 0; kt < 32; ++kt) {
        const int kb = kt * 64;
#pragma unroll
        for (int i = 0; i < 4; ++i) {
            const int r0 = wid * 32 + i * 8;
            __builtin_amdgcn_global_load_lds(GLOBAL_AS(srcA[i] + kb), LDS_AS(As + r0 * 64), 16, 0, 0);
            __builtin_amdgcn_global_load_lds(GLOBAL_AS(srcB[i] + kb), LDS_AS(Bs + r0 * 64), 16, 0, 0);
        }
        __syncthreads();

#pragma unroll
        for (int ks = 0; ks < 2; ++ks) {
            bf16x8 af[4], bg[4];
#pragma unroll
            for (int m = 0; m < 4; ++m) {
                const int row = wr * 64 + m * 16 + (lane & 15);
                const int c   = ks * 4 + (lane >> 4);
                const int p   = c ^ (row & 7);
                af[m] = *reinterpret_cast<const bf16x8*>(As + row * 64 + p * 8);
            }
#pragma unroll
            for (int n = 0; n < 4; ++n) {
                const int row = wc * 64 + n * 16 + (lane & 15);
                const int c   = ks * 4 + (lane >> 4);
                const int p   = c ^ (row & 7);
                bg[n] = *reinterpret_cast<const bf16x8*>(Bs + row * 64 + p * 8);
            }
#pragma unroll
            for (int m = 0; m < 4; ++m)
#pragma unroll
                for (int n = 0; n < 4; ++n)
                    acc[m][n] = __builtin_amdgcn_mfma_f32_16x16x32_bf16(af[m], bg[n], acc[m][n], 0, 0, 0);
        }
        __syncthreads();
    }

    // Epilogue: bias + activation, store f16. Gate region uniform per block.
    const int rgn = n0 >> 10;   // 0=z(tanh), 1=f, 2=o
#pragma unroll
    for (int m = 0; m < 4; ++m) {
#pragma unroll
        for (int n = 0; n < 4; ++n) {
            const int col = n0 + wc * 64 + n * 16 + (lane & 15);
            const float bv = bias[col];
#pragma unroll
            for (int v = 0; v < 4; ++v) {
                const int row = m0 + wr * 64 + m * 16 + ((lane >> 4) * 4) + v;
                const float g = acc[m][n][v] + bv;
                float val;
                if (rgn == 0) {
                    float s = 1.0f / (1.0f + __expf(-2.0f * g));
                    val = 2.0f * s - 1.0f;                       // tanh
                } else {
                    val = 1.0f / (1.0f + __expf(-g));            // sigmoid
                }
                G[(size_t)row * 3072 + col] = (_Float16)val;
            }
        }
    }
}

// ---------------------------------------------------------------------------
// Chunked parallel scan, 16 chunks of 64 steps (2x the waves of the 8-chunk
// version; scan is latency-bound so wave count dominates — round-11 lesson).
// Pass 1: compose (A,B) for chunks 0..14 (chunk 15 never consumed).
// ---------------------------------------------------------------------------
__global__ void scan_pass1(const _Float16* __restrict__ G, float2* __restrict__ AB) {
    const int bid = blockIdx.x;        // 480 = 8b x 15c x 4ug
    const int b   = bid / 60;
    const int r   = bid % 60;
    const int c   = r >> 2;            // chunk 0..14
    const int ug  = r & 3;
    const int u   = ug * 256 + threadIdx.x;
    const _Float16* g = G + (size_t)(b * 1024 + c * 64) * 3072 + u;
    float A = 1.f, Bv = 0.f;
#pragma unroll 8
    for (int i = 0; i < 64; ++i) {
        const float zv = (float)g[(size_t)i * 3072];
        const float fv = (float)g[(size_t)i * 3072 + 1024];
        const float ov = (float)g[(size_t)i * 3072 + 2048];
        const float a  = ov * fv;
        const float bb = ov * (1.f - fv) * zv;
        A  = a * A;
        Bv = a * Bv + bb;
    }
    AB[(size_t)(b * 16 + c) * 1024 + u] = make_float2(A, Bv);
}

// 2048 blocks x 64 threads (8b x 16c x 16ug) -> 8 waves/CU.
__global__ void scan_pass23(const _Float16* __restrict__ G, const float2* __restrict__ AB,
                            float* __restrict__ out) {
    const int bid = blockIdx.x;
    const int b   = bid >> 8;
    const int r   = bid & 255;
    const int c   = r >> 4;            // chunk 0..15 (block-uniform)
    const int ug  = r & 15;
    const int u   = ug * 64 + threadIdx.x;

    float h = 0.f;
    for (int j = 0; j < c; ++j) {      // block-uniform trip count (<=15)
        float2 p = AB[(size_t)(b * 16 + j) * 1024 + u];
        h = p.x * h + p.y;
    }
    const _Float16* g = G + (size_t)(b * 1024 + c * 64) * 3072 + u;
    float* o = out + (size_t)(b * 1024 + c * 64) * 1024 + u;
#pragma unroll 8
    for (int i = 0; i < 64; ++i) {
        const float zv = (float)g[(size_t)i * 3072];
        const float fv = (float)g[(size_t)i * 3072 + 1024];
        const float ov = (float)g[(size_t)i * 3072 + 2048];
        h = ov * (fv * h + (1.f - fv) * zv);
        o[(size_t)i * 1024] = h;
    }
}

// ---------------------------------------------------------------------------
extern "C" void kernel_launch(void* const* d_in, const int* in_sizes, int n_in,
                              void* d_out, int out_size, void* d_ws, size_t ws_size,
                              hipStream_t stream) {
    const float* x    = (const float*)d_in[0];   // [8,1024,1024]
    const float* kern = (const float*)d_in[1];   // [2,1024,3072]
    const float* bias = (const float*)d_in[2];   // [3072]
    float* out = (float*)d_out;                  // [8,1024,1024]

    char* ws = (char*)d_ws;
    unsigned short* xb2 = (unsigned short*)ws;                  // 8200*1024*2 = 16,793,600 B
    unsigned short* KT  = (unsigned short*)(ws + 16793600);     // 12,582,912 B
    _Float16* G         = (_Float16*)(ws + 29376512);           // 50,331,648 B
    float2* AB          = (float2*)(ws + 79708160);             //  1,048,576 B

    prep_inputs<<<dim3(1536 + 8200), dim3(256), 0, stream>>>(x, kern, xb2, KT);
    gemm_gates<<<dim3(24, 64), dim3(256), 0, stream>>>(xb2, KT, bias, G);
    scan_pass1<<<dim3(480), dim3(256), 0, stream>>>(G, AB);
    scan_pass23<<<dim3(2048), dim3(64), 0, stream>>>(G, AB, out);
}